// Round 2
// baseline (159.318 us; speedup 1.0000x reference)
//
#include <hip/hip_runtime.h>
#include <math.h>

// Problem constants (from setup_inputs): H=1024, B=32, S=4096, all f32.
constexpr int H = 1024;
constexpr int B = 32;
constexpr int S = 4096;
constexpr int STILE = 64;   // s-rows per block in energies kernel

// ---------------------------------------------------------------------------
// Kernel 1: v[b,h] = sum_g hidden[b,g] * W[g,h]
// Grid: 32 b x 8 h-chunks(128 wide) = 256 blocks, 256 threads.
// Thread layout: hq = tid&31 (h-quad within chunk), gg = tid>>5 (8-way split
// of the g-reduction). Each thread: 128 g-iters of float4 W loads (coalesced,
// W is L2-resident), 4 independent float4 accumulators, LDS combine of the
// 8 partials. ~4 waves/CU + 4-deep MLP hides L2 latency.
// ---------------------------------------------------------------------------
__global__ __launch_bounds__(256) void compute_v_kernel(
    const float* __restrict__ hidden, const float* __restrict__ W,
    float* __restrict__ v)
{
    const int b  = blockIdx.x >> 3;
    const int hc = blockIdx.x & 7;            // 128-wide h chunk
    const int hq = threadIdx.x & 31;          // h-quad within chunk
    const int gg = threadIdx.x >> 5;          // 0..7
    const int hquad = hc * 32 + hq;           // global h/4 index
    const float* __restrict__ hb = hidden + b * H;
    const float4* __restrict__ W4 = (const float4*)W;   // W4[g*256 + h/4]

    float4 a0 = {0,0,0,0}, a1 = {0,0,0,0}, a2 = {0,0,0,0}, a3 = {0,0,0,0};
    const int g0 = gg * 128;
    #pragma unroll 8
    for (int g = g0; g < g0 + 128; g += 4) {
        float4 w0 = W4[(g + 0) * 256 + hquad];
        float4 w1 = W4[(g + 1) * 256 + hquad];
        float4 w2 = W4[(g + 2) * 256 + hquad];
        float4 w3 = W4[(g + 3) * 256 + hquad];
        float h0 = hb[g + 0], h1 = hb[g + 1], h2 = hb[g + 2], h3 = hb[g + 3];
        a0.x = fmaf(h0, w0.x, a0.x); a0.y = fmaf(h0, w0.y, a0.y);
        a0.z = fmaf(h0, w0.z, a0.z); a0.w = fmaf(h0, w0.w, a0.w);
        a1.x = fmaf(h1, w1.x, a1.x); a1.y = fmaf(h1, w1.y, a1.y);
        a1.z = fmaf(h1, w1.z, a1.z); a1.w = fmaf(h1, w1.w, a1.w);
        a2.x = fmaf(h2, w2.x, a2.x); a2.y = fmaf(h2, w2.y, a2.y);
        a2.z = fmaf(h2, w2.z, a2.z); a2.w = fmaf(h2, w2.w, a2.w);
        a3.x = fmaf(h3, w3.x, a3.x); a3.y = fmaf(h3, w3.y, a3.y);
        a3.z = fmaf(h3, w3.z, a3.z); a3.w = fmaf(h3, w3.w, a3.w);
    }
    float4 acc;
    acc.x = (a0.x + a1.x) + (a2.x + a3.x);
    acc.y = (a0.y + a1.y) + (a2.y + a3.y);
    acc.z = (a0.z + a1.z) + (a2.z + a3.z);
    acc.w = (a0.w + a1.w) + (a2.w + a3.w);

    __shared__ float4 part[8][32];
    part[gg][hq] = acc;
    __syncthreads();
    if (gg == 0) {
        float4 s = part[0][hq];
        #pragma unroll
        for (int k = 1; k < 8; ++k) {
            float4 p = part[k][hq];
            s.x += p.x; s.y += p.y; s.z += p.z; s.w += p.w;
        }
        ((float4*)(v + b * H))[hquad] = s;
    }
}

// ---------------------------------------------------------------------------
// Kernel 2: energies[b,s] = v[b,:] . enc[s,b,:]   (bias cancels in softmax
// via shift invariance). One wave per (s,b) row; each lane's 16 v-values are
// row-invariant -> hoisted into 4 float4 REGISTERS once per block (no LDS,
// no barrier). float4 enc loads = 1 KiB per wave-instruction, coalesced.
// ---------------------------------------------------------------------------
__global__ __launch_bounds__(256) void energies_kernel(
    const float* __restrict__ enc, const float* __restrict__ v,
    float* __restrict__ energies)
{
    constexpr int tilesPerB = S / STILE;              // 64
    const int b  = blockIdx.x / tilesPerB;
    const int s0 = (blockIdx.x % tilesPerB) * STILE;
    const int wave = threadIdx.x >> 6;
    const int lane = threadIdx.x & 63;

    const float4* __restrict__ vb = (const float4*)(v + b * H);
    const float4 w0 = vb[lane], w1 = vb[64 + lane],
                 w2 = vb[128 + lane], w3 = vb[192 + lane];

    for (int si = wave; si < STILE; si += 4) {
        const int s = s0 + si;
        const float4* __restrict__ row =
            (const float4*)(enc + ((size_t)s * B + b) * H);
        float4 e0 = row[lane], e1 = row[64 + lane],
               e2 = row[128 + lane], e3 = row[192 + lane];
        float p0 = e0.x * w0.x, p1 = e1.x * w1.x;
        p0 = fmaf(e0.y, w0.y, p0); p1 = fmaf(e1.y, w1.y, p1);
        p0 = fmaf(e0.z, w0.z, p0); p1 = fmaf(e1.z, w1.z, p1);
        p0 = fmaf(e0.w, w0.w, p0); p1 = fmaf(e1.w, w1.w, p1);
        p0 = fmaf(e2.x, w2.x, p0); p1 = fmaf(e3.x, w3.x, p1);
        p0 = fmaf(e2.y, w2.y, p0); p1 = fmaf(e3.y, w3.y, p1);
        p0 = fmaf(e2.z, w2.z, p0); p1 = fmaf(e3.z, w3.z, p1);
        p0 = fmaf(e2.w, w2.w, p0); p1 = fmaf(e3.w, w3.w, p1);
        float acc = p0 + p1;
        #pragma unroll
        for (int off = 32; off > 0; off >>= 1)
            acc += __shfl_xor(acc, off, 64);
        if (lane == 0) energies[b * S + s] = acc;
    }
}

// ---------------------------------------------------------------------------
// Kernel 3: in-place row softmax over d_out[b, 0, :]. One block per b;
// row cached in 4 float4 registers/thread: 1 read + 1 write of HBM.
// ---------------------------------------------------------------------------
__global__ __launch_bounds__(256) void softmax_kernel(float* __restrict__ out)
{
    const int b = blockIdx.x;
    float4* __restrict__ row = (float4*)(out + (size_t)b * S);
    __shared__ float redm[4];
    __shared__ float reds[4];
    const int wave = threadIdx.x >> 6;
    const int lane = threadIdx.x & 63;

    float4 vals[4];                       // 16 values/thread
    float m = -INFINITY;
    #pragma unroll
    for (int k = 0; k < 4; ++k) {
        vals[k] = row[threadIdx.x + k * 256];
        m = fmaxf(m, fmaxf(fmaxf(vals[k].x, vals[k].y),
                           fmaxf(vals[k].z, vals[k].w)));
    }
    #pragma unroll
    for (int off = 32; off > 0; off >>= 1)
        m = fmaxf(m, __shfl_xor(m, off, 64));
    if (lane == 0) redm[wave] = m;
    __syncthreads();
    m = fmaxf(fmaxf(redm[0], redm[1]), fmaxf(redm[2], redm[3]));

    float ssum = 0.f;
    #pragma unroll
    for (int k = 0; k < 4; ++k) {
        vals[k].x = __expf(vals[k].x - m);
        vals[k].y = __expf(vals[k].y - m);
        vals[k].z = __expf(vals[k].z - m);
        vals[k].w = __expf(vals[k].w - m);
        ssum += (vals[k].x + vals[k].y) + (vals[k].z + vals[k].w);
    }
    #pragma unroll
    for (int off = 32; off > 0; off >>= 1)
        ssum += __shfl_xor(ssum, off, 64);
    if (lane == 0) reds[wave] = ssum;
    __syncthreads();
    const float inv = 1.0f / ((reds[0] + reds[1]) + (reds[2] + reds[3]));
    #pragma unroll
    for (int k = 0; k < 4; ++k) {
        float4 o = vals[k];
        o.x *= inv; o.y *= inv; o.z *= inv; o.w *= inv;
        row[threadIdx.x + k * 256] = o;
    }
}

extern "C" void kernel_launch(void* const* d_in, const int* in_sizes, int n_in,
                              void* d_out, int out_size, void* d_ws, size_t ws_size,
                              hipStream_t stream) {
    const float* hidden = (const float*)d_in[0];   // [1, B, H]
    const float* enc    = (const float*)d_in[1];   // [S, B, H]
    const float* W      = (const float*)d_in[2];   // [H, H]
    // d_in[3] = attn_b: per-b constant in energies -> cancels under softmax.
    float* out = (float*)d_out;                    // [B, 1, S]
    float* v   = (float*)d_ws;                     // B*H floats = 128 KiB

    compute_v_kernel<<<dim3(B * 8), dim3(256), 0, stream>>>(hidden, W, v);
    energies_kernel<<<dim3(B * (S / STILE)), dim3(256), 0, stream>>>(enc, v, out);
    softmax_kernel<<<dim3(B), dim3(256), 0, stream>>>(out);
}